// Round 1
// baseline (288.315 us; speedup 1.0000x reference)
//
#include <hip/hip_runtime.h>
#include <stdint.h>

#define N_ROWS 4096
#define DIM    1024
#define NCLS   64
#define EPSV   0.1f

typedef __attribute__((ext_vector_type(4))) float f32x4;
typedef __attribute__((ext_vector_type(4))) int   i32x4;
typedef __attribute__((ext_vector_type(8))) int   i32x8;

__device__ __forceinline__ void async_cp16(const void* g, void* l) {
    __builtin_amdgcn_global_load_lds((const __attribute__((address_space(1))) void*)g,
                                     (__attribute__((address_space(3))) void*)l,
                                     16, 0, 0);
}

__device__ __forceinline__ float softplus(float x) {
    return fmaxf(x, 0.f) + __logf(1.f + __expf(-fabsf(x)));
}

// ---------------- K1: per-class sum/sqsum via row gather (unchanged) ---------
__global__ __launch_bounds__(256) void k_cstats(const float* __restrict__ X,
                                                const int* __restrict__ tgt,
                                                float* __restrict__ csumR,
                                                float* __restrict__ csqR) {
    __shared__ int rows[N_ROWS];
    __shared__ int nrows_s;
    int tid = threadIdx.x;
    int c = blockIdx.x >> 2, q = blockIdx.x & 3;
    if (tid == 0) nrows_s = 0;
    __syncthreads();
    for (int i = tid; i < N_ROWS; i += 256)
        if (tgt[i] == c) { int p = atomicAdd(&nrows_s, 1); rows[p] = i; }
    __syncthreads();
    int n = nrows_s;
    int d = q * 256 + tid;
    float s = 0.f, qq = 0.f;
    #pragma unroll 4
    for (int r = 0; r < n; r++) {
        float x = X[(size_t)rows[r] * DIM + d];
        s += x; qq += x * x;
    }
    csumR[c * DIM + d] = s;
    csqR [c * DIM + d] = qq;
}

// ---------------- K2: counts + weights + fp8 scale + zero loss (unchanged) ---
__global__ __launch_bounds__(128) void k_weights(const int* __restrict__ tgt,
                                                 const float* __restrict__ csumR,
                                                 const float* __restrict__ csqR,
                                                 float* __restrict__ w,
                                                 float* __restrict__ scal,
                                                 float* __restrict__ loss_out) {
    __shared__ int hist[NCLS];
    __shared__ float redw[2];
    int tid = threadIdx.x, b = blockIdx.x;
    if (tid < NCLS) hist[tid] = 0;
    __syncthreads();
    for (int i = tid; i < N_ROWS; i += 128) atomicAdd(&hist[tgt[i]], 1);
    __syncthreads();
    long long sp = 0, ss = 0;
    for (int c = 0; c < NCLS; c++) { long long cc = hist[c]; sp += cc * (cc - 1); ss += cc * cc; }
    float cnt_pos = (float)sp;
    float cnt_neg = (float)((long long)N_ROWS * N_ROWS - ss);
    int d = b * 128 + tid;
    float A = 0.f, X2 = 0.f, T = 0.f, SS = 0.f;
    #pragma unroll 8
    for (int c = 0; c < NCLS; c++) {
        float s = csumR[c * DIM + d];
        float q = csqR [c * DIM + d];
        A += (float)hist[c] * q; X2 += q; T += s; SS += s * s;
    }
    float posnum = 2.f * (A - SS);
    float negnum = 2.f * ((float)N_ROWS * X2 - A - T * T + SS);
    float wd = cnt_neg / (negnum + EPSV) - cnt_pos / (posnum + EPSV);
    w[d] = wd;
    float m = wd * wd;
    for (int off = 32; off; off >>= 1) m += __shfl_down(m, off, 64);
    int wv = tid >> 6, ln = tid & 63;
    if (ln == 0) redw[wv] = m;
    __syncthreads();
    if (b == 0 && tid == 0) {
        float ms = (redw[0] + redw[1]) / 128.f;
        scal[0] = exp2f(roundf(log2f(sqrtf(ms) + 1e-30f)));
        loss_out[0] = 0.0f;
    }
}

// ---------------- K3: xw, sq (fp32 exact), fp8 casts, PLAIN row-major --------
// Swizzle is no longer baked here; the MX gemm pre-swizzles its global source
// addresses instead (global_load_lds writes linearly, rule #21).
__global__ __launch_bounds__(256) void k_prep(const float* __restrict__ X,
                                              const float* __restrict__ w,
                                              const float* __restrict__ scal,
                                              unsigned int* __restrict__ Xb8,
                                              unsigned int* __restrict__ XWb8,
                                              float* __restrict__ sq) {
    int row = blockIdx.x, tid = threadIdx.x;
    float inv_sw = 1.0f / scal[0];
    float4 x  = ((const float4*)(X + (size_t)row * DIM))[tid];
    float4 ww = ((const float4*)w)[tid];
    float4 xw = make_float4(x.x * ww.x, x.y * ww.y, x.z * ww.z, x.w * ww.w);
    float p = x.x * xw.x + x.y * xw.y + x.z * xw.z + x.w * xw.w;
    unsigned ux = __builtin_amdgcn_cvt_pk_fp8_f32(x.x, x.y, 0, false);
    ux = __builtin_amdgcn_cvt_pk_fp8_f32(x.z, x.w, ux, true);
    unsigned uw = __builtin_amdgcn_cvt_pk_fp8_f32(xw.x * inv_sw, xw.y * inv_sw, 0, false);
    uw = __builtin_amdgcn_cvt_pk_fp8_f32(xw.z * inv_sw, xw.w * inv_sw, uw, true);
    int widx = row * 256 + tid;            // plain row-major fp8
    Xb8 [widx] = ux;
    XWb8[widx] = uw;
    for (int off = 32; off; off >>= 1) p += __shfl_down(p, off, 64);
    __shared__ float red[4];
    int wv = tid >> 6, ln = tid & 63;
    if (ln == 0) red[wv] = p;
    __syncthreads();
    if (tid == 0) sq[row] = red[0] + red[1] + red[2] + red[3];
}

// ---------------- K4: MX-fp8 (scale=1) MFMA gram + softplus + masked mean ----
// mfma_scale_f32_16x16x128_f8f6f4 with E8M0 scale 127 (=1.0): bit-identical
// fp8 products at 2x the non-scaled fp8 issue rate (m148 ladder: x1.64).
// 256 thr = 4 waves, block tile 128x128, wave tile 64x64 (4x4 16x16 frags,
// 64 acc VGPRs). K-step = 128 B/row, single-buffered 2-barrier loop (m97/m148
// structure), occupancy ~3-4 blocks/CU hides the stage stall.
// LDS granule swizzle: phys16B = logical16B ^ (row&7); applied on the global
// SOURCE address at stage time (linear LDS dest) and on the ds_read address.
__global__ __launch_bounds__(256, 3) void k_gemm_loss(const unsigned char* __restrict__ Xb8,
                                                      const unsigned char* __restrict__ XWb8,
                                                      const float* __restrict__ sq,
                                                      const int* __restrict__ tgt,
                                                      const float* __restrict__ scal,
                                                      float* __restrict__ loss) {
    __shared__ __align__(16) unsigned char As[16384];   // 128 rows x 128 B (one K-step)
    __shared__ __align__(16) unsigned char Bs[16384];
    __shared__ float sqI[128], sqJ[128];
    __shared__ int   tIs[128], tJs[128];
    __shared__ float red[4];

    int tid = threadIdx.x;
    int wave = tid >> 6, lane = tid & 63;

    // balanced triangular decode (32x32 tile grid, 528 tiles)
    int g = blockIdx.x & 7, s = blockIdx.x >> 3;
    int j0 = g, j1 = 15 - g, j2 = 16 + g;
    int n0 = j0 + 1, n1 = j1 + 1, n2 = j2 + 1;
    int jt, it;
    if      (s < n0)           { jt = j0; it = s; }
    else if (s < n0 + n1)      { jt = j1; it = s - n0; }
    else if (s < n0 + n1 + n2) { jt = j2; it = s - n0 - n1; }
    else                       { jt = 31 - g; it = s - n0 - n1 - n2; }

    // staging source pointers: 8 issues/thread/step (4 A + 4 B), 16 B each.
    // issue i of wave w covers LDS rows (w*4+i)*8 .. +8; lane l -> row +l>>3,
    // phys granule l&7; global src holds logical granule (l&7)^(row&7).
    const unsigned char* Abase = Xb8  + (size_t)(it * 128) * DIM;
    const unsigned char* Bbase = XWb8 + (size_t)(jt * 128) * DIM;
    const unsigned char* gpA[4];
    const unsigned char* gpB[4];
    int ldo[4];
    #pragma unroll
    for (int i = 0; i < 4; i++) {
        int r  = (wave * 4 + i) * 8 + (lane >> 3);
        int pg = lane & 7;
        size_t off = (size_t)r * DIM + (size_t)((pg ^ (r & 7)) << 4);
        gpA[i] = Abase + off;
        gpB[i] = Bbase + off;
        ldo[i] = (wave * 4 + i) * 1024;          // wave-uniform LDS base
    }

    // fragment LDS byte offsets (step-invariant, single buffer)
    int lr = lane & 15, hk = lane >> 4;          // hk = K-granule-pair group
    int wrow = (wave >> 1) * 64, wcol = (wave & 1) * 64;
    int offA[4], offB[4];
    #pragma unroll
    for (int mi = 0; mi < 4; mi++) {
        int r = wrow + mi * 16 + lr;
        offA[mi] = r * 128 + (((hk * 2) ^ (r & 7)) << 4);
    }
    #pragma unroll
    for (int nj = 0; nj < 4; nj++) {
        int c = wcol + nj * 16 + lr;
        offB[nj] = c * 128 + (((hk * 2) ^ (c & 7)) << 4);
    }

    f32x4 acc[4][4];
    #pragma unroll
    for (int i = 0; i < 4; i++)
        #pragma unroll
        for (int j = 0; j < 4; j++) acc[i][j] = (f32x4){0.f, 0.f, 0.f, 0.f};

    for (int st = 0; st < 8; st++) {             // 8 K-steps of 128
        __syncthreads();                          // buffer free (prev reads done)
        #pragma unroll
        for (int i = 0; i < 4; i++) async_cp16(gpA[i] + st * 128, As + ldo[i]);
        #pragma unroll
        for (int i = 0; i < 4; i++) async_cp16(gpB[i] + st * 128, Bs + ldo[i]);
        asm volatile("s_waitcnt vmcnt(0)" ::: "memory");
        __syncthreads();                          // whole tile staged

        i32x8 bv[4];
        #pragma unroll
        for (int nj = 0; nj < 4; nj++) {
            i32x4 lo = *(const i32x4*)(Bs + offB[nj]);
            i32x4 hi = *(const i32x4*)(Bs + (offB[nj] ^ 16));
            bv[nj] = __builtin_shufflevector(lo, hi, 0, 1, 2, 3, 4, 5, 6, 7);
        }
        #pragma unroll
        for (int mi = 0; mi < 4; mi++) {
            i32x4 lo = *(const i32x4*)(As + offA[mi]);
            i32x4 hi = *(const i32x4*)(As + (offA[mi] ^ 16));
            i32x8 av = __builtin_shufflevector(lo, hi, 0, 1, 2, 3, 4, 5, 6, 7);
            #pragma unroll
            for (int nj = 0; nj < 4; nj++)
                acc[mi][nj] = __builtin_amdgcn_mfma_scale_f32_16x16x128_f8f6f4(
                    av, bv[nj], acc[mi][nj], 0, 0, 0, 127, 0, 127);
        }
    }

    // epilogue: S = sq_i + sq_j - 2*sw*G', masked softplus, x2 off-diagonal
    __syncthreads();
    if (tid < 128)      { sqI[tid] = sq[it * 128 + tid]; tIs[tid] = tgt[it * 128 + tid]; }
    else                { int u = tid - 128; sqJ[u] = sq[jt * 128 + u]; tJs[u] = tgt[jt * 128 + u]; }
    __syncthreads();

    float sw2 = 2.0f * scal[0];
    float sum = 0.f;
    bool diagTile = (it == jt);
    #pragma unroll
    for (int j = 0; j < 4; j++) {
        int col = wcol + j * 16 + (lane & 15);            // C/D: col = lane&15
        float sj = sqJ[col]; int tj = tJs[col];
        #pragma unroll
        for (int i = 0; i < 4; i++) {
            int rbase = wrow + i * 16 + (lane >> 4) * 4;  // C/D: row = quad*4+reg
            #pragma unroll
            for (int rr = 0; rr < 4; rr++) {
                int rowp = rbase + rr;
                float S = sqI[rowp] + sj - sw2 * acc[i][j][rr];
                float v;
                if (tIs[rowp] == tj) v = (diagTile && rowp == col) ? 0.f : softplus(-S);
                else                 v = softplus(S);
                sum += v;
            }
        }
    }
    float scale = (diagTile ? 1.f : 2.f) * (1.f / ((float)N_ROWS * (float)(N_ROWS - 1)));
    sum *= scale;
    for (int off = 32; off; off >>= 1) sum += __shfl_down(sum, off, 64);
    if (lane == 0) red[wave] = sum;
    __syncthreads();
    if (tid == 0) {
        float t = red[0] + red[1] + red[2] + red[3];
        atomicAdd(loss, t);
    }
}

extern "C" void kernel_launch(void* const* d_in, const int* in_sizes, int n_in,
                              void* d_out, int out_size, void* d_ws, size_t ws_size,
                              hipStream_t stream) {
    const float* X  = (const float*)d_in[0];
    const int* tgt  = (const int*)d_in[1];
    float* out = (float*)d_out;
    char* ws = (char*)d_ws;
    const size_t MB = 1u << 20;

    float* w      = (float*)ws;                         // 4 KB
    float* sq     = (float*)(ws + 4096);                // 16 KB
    float* scal   = (float*)(ws + 24576);               // 4 B
    unsigned int* Xb8  = (unsigned int*)(ws + 1 * MB);  // 4 MB
    unsigned int* XWb8 = (unsigned int*)(ws + 5 * MB);  // 4 MB
    float* csumR  = (float*)(ws + 9 * MB);              // 256 KB
    float* csqR   = (float*)(ws + 9 * MB + 256 * 1024); // 256 KB

    k_cstats  <<<256,  256, 0, stream>>>(X, tgt, csumR, csqR);
    k_weights <<<8,    128, 0, stream>>>(tgt, csumR, csqR, w, scal, out);
    k_prep    <<<4096, 256, 0, stream>>>(X, w, scal, Xb8, XWb8, sq);
    k_gemm_loss<<<528, 256, 0, stream>>>((const unsigned char*)Xb8, (const unsigned char*)XWb8,
                                         sq, tgt, scal, out);
}

// Round 2
// 155.283 us; speedup vs baseline: 1.8567x; 1.8567x over previous
//
#include <hip/hip_runtime.h>
#include <stdint.h>

#define N_ROWS 4096
#define DIM    1024
#define NCLS   64
#define EPSV   0.1f

typedef __attribute__((ext_vector_type(4))) float f32x4;
typedef __attribute__((ext_vector_type(4))) int   i32x4;
typedef __attribute__((ext_vector_type(8))) int   i32x8;

__device__ __forceinline__ void async_cp16(const void* g, void* l) {
    __builtin_amdgcn_global_load_lds((const __attribute__((address_space(1))) void*)g,
                                     (__attribute__((address_space(3))) void*)l,
                                     16, 0, 0);
}

__device__ __forceinline__ float softplus(float x) {
    return fmaxf(x, 0.f) + __logf(1.f + __expf(-fabsf(x)));
}

// ---------------- K1: per-class sum/sqsum via row gather (unchanged) ---------
__global__ __launch_bounds__(256) void k_cstats(const float* __restrict__ X,
                                                const int* __restrict__ tgt,
                                                float* __restrict__ csumR,
                                                float* __restrict__ csqR) {
    __shared__ int rows[N_ROWS];
    __shared__ int nrows_s;
    int tid = threadIdx.x;
    int c = blockIdx.x >> 2, q = blockIdx.x & 3;
    if (tid == 0) nrows_s = 0;
    __syncthreads();
    for (int i = tid; i < N_ROWS; i += 256)
        if (tgt[i] == c) { int p = atomicAdd(&nrows_s, 1); rows[p] = i; }
    __syncthreads();
    int n = nrows_s;
    int d = q * 256 + tid;
    float s = 0.f, qq = 0.f;
    #pragma unroll 4
    for (int r = 0; r < n; r++) {
        float x = X[(size_t)rows[r] * DIM + d];
        s += x; qq += x * x;
    }
    csumR[c * DIM + d] = s;
    csqR [c * DIM + d] = qq;
}

// ---------------- K2: counts + weights + fp8 scale + zero loss (unchanged) ---
__global__ __launch_bounds__(128) void k_weights(const int* __restrict__ tgt,
                                                 const float* __restrict__ csumR,
                                                 const float* __restrict__ csqR,
                                                 float* __restrict__ w,
                                                 float* __restrict__ scal,
                                                 float* __restrict__ loss_out) {
    __shared__ int hist[NCLS];
    __shared__ float redw[2];
    int tid = threadIdx.x, b = blockIdx.x;
    if (tid < NCLS) hist[tid] = 0;
    __syncthreads();
    for (int i = tid; i < N_ROWS; i += 128) atomicAdd(&hist[tgt[i]], 1);
    __syncthreads();
    long long sp = 0, ss = 0;
    for (int c = 0; c < NCLS; c++) { long long cc = hist[c]; sp += cc * (cc - 1); ss += cc * cc; }
    float cnt_pos = (float)sp;
    float cnt_neg = (float)((long long)N_ROWS * N_ROWS - ss);
    int d = b * 128 + tid;
    float A = 0.f, X2 = 0.f, T = 0.f, SS = 0.f;
    #pragma unroll 8
    for (int c = 0; c < NCLS; c++) {
        float s = csumR[c * DIM + d];
        float q = csqR [c * DIM + d];
        A += (float)hist[c] * q; X2 += q; T += s; SS += s * s;
    }
    float posnum = 2.f * (A - SS);
    float negnum = 2.f * ((float)N_ROWS * X2 - A - T * T + SS);
    float wd = cnt_neg / (negnum + EPSV) - cnt_pos / (posnum + EPSV);
    w[d] = wd;
    float m = wd * wd;
    for (int off = 32; off; off >>= 1) m += __shfl_down(m, off, 64);
    int wv = tid >> 6, ln = tid & 63;
    if (ln == 0) redw[wv] = m;
    __syncthreads();
    if (b == 0 && tid == 0) {
        float ms = (redw[0] + redw[1]) / 128.f;
        scal[0] = exp2f(roundf(log2f(sqrtf(ms) + 1e-30f)));
        loss_out[0] = 0.0f;
    }
}

// ---------------- K3: xw, sq (fp32 exact), fp8 casts, PLAIN row-major --------
// Swizzle is baked into the MX gemm's global source addresses instead
// (global_load_lds writes linearly, rule #21).
__global__ __launch_bounds__(256) void k_prep(const float* __restrict__ X,
                                              const float* __restrict__ w,
                                              const float* __restrict__ scal,
                                              unsigned int* __restrict__ Xb8,
                                              unsigned int* __restrict__ XWb8,
                                              float* __restrict__ sq) {
    int row = blockIdx.x, tid = threadIdx.x;
    float inv_sw = 1.0f / scal[0];
    float4 x  = ((const float4*)(X + (size_t)row * DIM))[tid];
    float4 ww = ((const float4*)w)[tid];
    float4 xw = make_float4(x.x * ww.x, x.y * ww.y, x.z * ww.z, x.w * ww.w);
    float p = x.x * xw.x + x.y * xw.y + x.z * xw.z + x.w * xw.w;
    unsigned ux = __builtin_amdgcn_cvt_pk_fp8_f32(x.x, x.y, 0, false);
    ux = __builtin_amdgcn_cvt_pk_fp8_f32(x.z, x.w, ux, true);
    unsigned uw = __builtin_amdgcn_cvt_pk_fp8_f32(xw.x * inv_sw, xw.y * inv_sw, 0, false);
    uw = __builtin_amdgcn_cvt_pk_fp8_f32(xw.z * inv_sw, xw.w * inv_sw, uw, true);
    int widx = row * 256 + tid;            // plain row-major fp8
    Xb8 [widx] = ux;
    XWb8[widx] = uw;
    for (int off = 32; off; off >>= 1) p += __shfl_down(p, off, 64);
    __shared__ float red[4];
    int wv = tid >> 6, ln = tid & 63;
    if (ln == 0) red[wv] = p;
    __syncthreads();
    if (tid == 0) sq[row] = red[0] + red[1] + red[2] + red[3];
}

// ---------------- K4: MX-fp8 (scale=1) MFMA gram + softplus + masked mean ----
// mfma_scale_f32_16x16x128_f8f6f4 with E8M0 scale 127 (=1.0): bit-identical
// fp8 products at 2x the non-scaled fp8 issue rate.
// 256 thr = 4 waves, block tile 128x128, wave tile 64x64 (4x4 16x16 frags).
// K-step = 128 B/row, single-buffered 2-barrier loop.
// NOTE: no min-waves-per-EU in launch_bounds — R1's (256,3) capped the
// unified VGPR/AGPR budget at ~170 and the allocator spilled the MFMA
// operand arrays to scratch (248 MB WRITE_SIZE, 200 us). Let the allocator
// take ~150-200 VGPRs; 2-3 waves/SIMD is enough here.
__global__ __launch_bounds__(256) void k_gemm_loss(const unsigned char* __restrict__ Xb8,
                                                   const unsigned char* __restrict__ XWb8,
                                                   const float* __restrict__ sq,
                                                   const int* __restrict__ tgt,
                                                   const float* __restrict__ scal,
                                                   float* __restrict__ loss) {
    __shared__ __align__(16) unsigned char As[16384];   // 128 rows x 128 B (one K-step)
    __shared__ __align__(16) unsigned char Bs[16384];
    __shared__ float sqI[128], sqJ[128];
    __shared__ int   tIs[128], tJs[128];
    __shared__ float red[4];

    int tid = threadIdx.x;
    int wave = tid >> 6, lane = tid & 63;

    // balanced triangular decode (32x32 tile grid, 528 tiles)
    int g = blockIdx.x & 7, s = blockIdx.x >> 3;
    int j0 = g, j1 = 15 - g, j2 = 16 + g;
    int n0 = j0 + 1, n1 = j1 + 1, n2 = j2 + 1;
    int jt, it;
    if      (s < n0)           { jt = j0; it = s; }
    else if (s < n0 + n1)      { jt = j1; it = s - n0; }
    else if (s < n0 + n1 + n2) { jt = j2; it = s - n0 - n1; }
    else                       { jt = 31 - g; it = s - n0 - n1 - n2; }

    // staging source pointers: 8 issues/thread/step (4 A + 4 B), 16 B each.
    // issue i of wave w covers LDS rows (w*4+i)*8 .. +8; lane l -> row +l>>3,
    // phys granule l&7; global src holds logical granule (l&7)^(row&7).
    const unsigned char* Abase = Xb8  + (size_t)(it * 128) * DIM;
    const unsigned char* Bbase = XWb8 + (size_t)(jt * 128) * DIM;
    const unsigned char* gpA[4];
    const unsigned char* gpB[4];
    int ldo[4];
    #pragma unroll
    for (int i = 0; i < 4; i++) {
        int r  = (wave * 4 + i) * 8 + (lane >> 3);
        int pg = lane & 7;
        size_t off = (size_t)r * DIM + (size_t)((pg ^ (r & 7)) << 4);
        gpA[i] = Abase + off;
        gpB[i] = Bbase + off;
        ldo[i] = (wave * 4 + i) * 1024;          // wave-uniform LDS base
    }

    // fragment LDS byte offsets (step-invariant, single buffer)
    int lr = lane & 15, hk = lane >> 4;          // hk = K-granule-pair group
    int wrow = (wave >> 1) * 64, wcol = (wave & 1) * 64;
    int offA[4], offB[4];
    #pragma unroll
    for (int mi = 0; mi < 4; mi++) {
        int r = wrow + mi * 16 + lr;
        offA[mi] = r * 128 + (((hk * 2) ^ (r & 7)) << 4);
    }
    #pragma unroll
    for (int nj = 0; nj < 4; nj++) {
        int c = wcol + nj * 16 + lr;
        offB[nj] = c * 128 + (((hk * 2) ^ (c & 7)) << 4);
    }

    f32x4 acc[4][4];
    #pragma unroll
    for (int i = 0; i < 4; i++)
        #pragma unroll
        for (int j = 0; j < 4; j++) acc[i][j] = (f32x4){0.f, 0.f, 0.f, 0.f};

    for (int st = 0; st < 8; st++) {             // 8 K-steps of 128
        __syncthreads();                          // buffer free (prev reads done)
        #pragma unroll
        for (int i = 0; i < 4; i++) async_cp16(gpA[i] + st * 128, As + ldo[i]);
        #pragma unroll
        for (int i = 0; i < 4; i++) async_cp16(gpB[i] + st * 128, Bs + ldo[i]);
        asm volatile("s_waitcnt vmcnt(0)" ::: "memory");
        __syncthreads();                          // whole tile staged

        i32x8 bv[4];
        #pragma unroll
        for (int nj = 0; nj < 4; nj++) {
            i32x4 lo = *(const i32x4*)(Bs + offB[nj]);
            i32x4 hi = *(const i32x4*)(Bs + (offB[nj] ^ 16));
            bv[nj] = __builtin_shufflevector(lo, hi, 0, 1, 2, 3, 4, 5, 6, 7);
        }
        #pragma unroll
        for (int mi = 0; mi < 4; mi++) {
            i32x4 lo = *(const i32x4*)(As + offA[mi]);
            i32x4 hi = *(const i32x4*)(As + (offA[mi] ^ 16));
            i32x8 av = __builtin_shufflevector(lo, hi, 0, 1, 2, 3, 4, 5, 6, 7);
            #pragma unroll
            for (int nj = 0; nj < 4; nj++)
                acc[mi][nj] = __builtin_amdgcn_mfma_scale_f32_16x16x128_f8f6f4(
                    av, bv[nj], acc[mi][nj], 0, 0, 0, 127, 0, 127);
        }
    }

    // epilogue: S = sq_i + sq_j - 2*sw*G', masked softplus, x2 off-diagonal
    __syncthreads();
    if (tid < 128)      { sqI[tid] = sq[it * 128 + tid]; tIs[tid] = tgt[it * 128 + tid]; }
    else                { int u = tid - 128; sqJ[u] = sq[jt * 128 + u]; tJs[u] = tgt[jt * 128 + u]; }
    __syncthreads();

    float sw2 = 2.0f * scal[0];
    float sum = 0.f;
    bool diagTile = (it == jt);
    #pragma unroll
    for (int j = 0; j < 4; j++) {
        int col = wcol + j * 16 + (lane & 15);            // C/D: col = lane&15
        float sj = sqJ[col]; int tj = tJs[col];
        #pragma unroll
        for (int i = 0; i < 4; i++) {
            int rbase = wrow + i * 16 + (lane >> 4) * 4;  // C/D: row = quad*4+reg
            #pragma unroll
            for (int rr = 0; rr < 4; rr++) {
                int rowp = rbase + rr;
                float S = sqI[rowp] + sj - sw2 * acc[i][j][rr];
                float v;
                if (tIs[rowp] == tj) v = (diagTile && rowp == col) ? 0.f : softplus(-S);
                else                 v = softplus(S);
                sum += v;
            }
        }
    }
    float scale = (diagTile ? 1.f : 2.f) * (1.f / ((float)N_ROWS * (float)(N_ROWS - 1)));
    sum *= scale;
    for (int off = 32; off; off >>= 1) sum += __shfl_down(sum, off, 64);
    if (lane == 0) red[wave] = sum;
    __syncthreads();
    if (tid == 0) {
        float t = red[0] + red[1] + red[2] + red[3];
        atomicAdd(loss, t);
    }
}

extern "C" void kernel_launch(void* const* d_in, const int* in_sizes, int n_in,
                              void* d_out, int out_size, void* d_ws, size_t ws_size,
                              hipStream_t stream) {
    const float* X  = (const float*)d_in[0];
    const int* tgt  = (const int*)d_in[1];
    float* out = (float*)d_out;
    char* ws = (char*)d_ws;
    const size_t MB = 1u << 20;

    float* w      = (float*)ws;                         // 4 KB
    float* sq     = (float*)(ws + 4096);                // 16 KB
    float* scal   = (float*)(ws + 24576);               // 4 B
    unsigned int* Xb8  = (unsigned int*)(ws + 1 * MB);  // 4 MB
    unsigned int* XWb8 = (unsigned int*)(ws + 5 * MB);  // 4 MB
    float* csumR  = (float*)(ws + 9 * MB);              // 256 KB
    float* csqR   = (float*)(ws + 9 * MB + 256 * 1024); // 256 KB

    k_cstats  <<<256,  256, 0, stream>>>(X, tgt, csumR, csqR);
    k_weights <<<8,    128, 0, stream>>>(tgt, csumR, csqR, w, scal, out);
    k_prep    <<<4096, 256, 0, stream>>>(X, w, scal, Xb8, XWb8, sq);
    k_gemm_loss<<<528, 256, 0, stream>>>((const unsigned char*)Xb8, (const unsigned char*)XWb8,
                                         sq, tgt, scal, out);
}